// Round 11
// baseline (87.922 us; speedup 1.0000x reference)
//
#include <hip/hip_runtime.h>
#include <hip/hip_bf16.h>

// out[4096,128] = bias + P @ W; P[r][k] = prod of x[r, subset_k], subsets are
// ALL k-combinations of range(32) in lexicographic order -> compile-time schedule.
// SINGLE dispatch: W is read directly from the fp32 inputs inside the K-loop
// (chunk->array mapping is compile-time; conversion identical to the old prep).
// Block = 64 rows x 32 cols, 512 threads = 8 waves = 2 rowtiles x 4 K-quarters.
// LDS fp32 reduce across K-quarters -> direct out write. No fences, no atomics.
constexpr int B_   = 4096;
constexpr int C_   = 128;
constexpr int K1   = 32;
constexpr int K2   = 496;
constexpr int K3   = 4960;
constexpr int KTOT = K1 + K2 + K3;    // 5488 = 343 * 16 exactly
constexpr int NCH  = KTOT / 16;       // 343 chunks of K=16
// chunk->array boundaries are exact: chunks [0,2)->W1, [2,33)->W2, [33,343)->W3
constexpr int Q0 = 0, Q1 = 86, Q2 = 172, Q3 = 258, Q4 = NCH;

typedef __attribute__((ext_vector_type(8)))  short bf16x8;
typedef __attribute__((ext_vector_type(16))) float f32x16;

// ---- compile-time subset schedule (lexicographic combinations; idx 32 -> xv[32]=1.0) ----
struct Sched { short a[KTOT]; short b[KTOT]; short c[KTOT]; };
constexpr Sched make_sched() {
    Sched s{}; int k = 0;
    for (int i = 0; i < 32; ++i) { s.a[k] = i; s.b[k] = 32; s.c[k] = 32; ++k; }
    for (int i = 0; i < 32; ++i)
        for (int j = i + 1; j < 32; ++j) { s.a[k] = i; s.b[k] = j; s.c[k] = 32; ++k; }
    for (int i = 0; i < 32; ++i)
        for (int j = i + 1; j < 32; ++j)
            for (int l = j + 1; l < 32; ++l) { s.a[k] = i; s.b[k] = j; s.c[k] = l; ++k; }
    return s;
}
constexpr Sched SCH = make_sched();

template<int K>
__device__ __forceinline__ float prodK(const float (&xv)[33]) {
    return xv[SCH.a[K]] * xv[SCH.b[K]] * xv[SCH.c[K]];   // static reg indices; pab CSE'd
}

template<int K0, int J>
__device__ __forceinline__ void prods8(const float (&xv)[33], bool hi, float (&q)[8]) {
    if constexpr (J < 8) {
        q[J] = hi ? prodK<K0 + 8 + J>(xv) : prodK<K0 + J>(xv);   // kg select
        prods8<K0, J + 1>(xv, hi, q);
    }
}

// chunks [CH, CHEND): B-frag loaded straight from fp32 W (compile-time array select)
template<int CH, int CHEND>
__device__ __forceinline__ void run_chunks(const float (&xv)[33], bool hi, int loff,
                                           const float* __restrict__ W1p,
                                           const float* __restrict__ W2p,
                                           const float* __restrict__ W3p,
                                           f32x16& acc) {
    if constexpr (CH < CHEND) {
        constexpr int K0    = CH * 16;
        constexpr int which = (K0 < K1) ? 0 : (K0 < K1 + K2 ? 1 : 2);
        constexpr int KOFF  = (which == 0) ? 0 : (which == 1 ? K1 : K1 + K2);
        const float* base = (which == 0) ? W1p : (which == 1 ? W2p : W3p);
        // lane's B-frag: B[k=K0+kg*8+j][n], 8 dword loads, each = 2x128B segments
        float wf[8];
        #pragma unroll
        for (int j = 0; j < 8; ++j)
            wf[j] = base[(size_t)(K0 - KOFF + j) * C_ + loff];
        // A-frag: lane's own 8 products, pure register VALU
        float q[8];
        prods8<K0, 0>(xv, hi, q);
        union { ushort us[8]; bf16x8 v; } af, bf;
        #pragma unroll
        for (int j = 0; j < 8; ++j) {
            __hip_bfloat16 ha = __float2bfloat16(q[j]);
            __hip_bfloat16 hb = __float2bfloat16(wf[j]);   // same cvt as old prep
            af.us[j] = *reinterpret_cast<ushort*>(&ha);
            bf.us[j] = *reinterpret_cast<ushort*>(&hb);
        }
        acc = __builtin_amdgcn_mfma_f32_32x32x16_bf16(af.v, bf.v, acc, 0, 0, 0);
        run_chunks<CH + 1, CHEND>(xv, hi, loff, W1p, W2p, W3p, acc);
    }
}

// main (only) kernel: 64 rows x 32 cols, 8 waves = 2 rowtiles x 4 K-quarters
__global__ __launch_bounds__(512, 2)
void poly_mfma(const float* __restrict__ x,
               const float* __restrict__ W1,
               const float* __restrict__ W2,
               const float* __restrict__ W3,
               const float* __restrict__ bias,
               float* __restrict__ out)
{
    __shared__ float red[8][32 * 33];     // per-wave accs; stride 33 -> conflict-free

    const int t    = threadIdx.x;
    const int lane = t & 63;
    const int w    = t >> 6;              // wave id 0..7
    const int kq   = w & 3;               // K-quarter
    const int rt   = w >> 2;              // rowtile 0/1
    const int m    = lane & 31;           // A row lane index / B col index
    const bool hi  = lane >= 32;          // kg
    const int row0 = blockIdx.x * 64;
    const int ct   = blockIdx.y;          // col tile: cols [ct*32, ct*32+32)
    const int loff = (hi ? 8 * C_ : 0) + ct * 32 + m;   // B-frag lane offset in W rows

    // lane's row -> 33 statically-indexed VGPRs (xv[32]=1.0 handles order<3)
    float xv[33];
    {
        const float4* xrow = (const float4*)(x + (size_t)(row0 + rt * 32 + m) * 32);
        #pragma unroll
        for (int qv = 0; qv < 8; ++qv) {
            float4 v = xrow[qv];
            xv[qv * 4 + 0] = v.x; xv[qv * 4 + 1] = v.y;
            xv[qv * 4 + 2] = v.z; xv[qv * 4 + 3] = v.w;
        }
        xv[32] = 1.0f;
    }

    f32x16 acc;
    #pragma unroll
    for (int i = 0; i < 16; ++i) acc[i] = 0.f;

    switch (kq) {
        case 0:  run_chunks<Q0, Q1>(xv, hi, loff, W1, W2, W3, acc); break;
        case 1:  run_chunks<Q1, Q2>(xv, hi, loff, W1, W2, W3, acc); break;
        case 2:  run_chunks<Q2, Q3>(xv, hi, loff, W1, W2, W3, acc); break;
        default: run_chunks<Q3, Q4>(xv, hi, loff, W1, W2, W3, acc); break;
    }

    // C/D layout (verified): col = lane&31, row = (e&3) + 8*(e>>2) + 4*kg
    const int kg = hi ? 1 : 0;
    #pragma unroll
    for (int e = 0; e < 16; ++e) {
        int r = (e & 3) + 8 * (e >> 2) + 4 * kg;
        red[w][r * 33 + m] = acc[e];
    }
    __syncthreads();

    // out = bias + kq0 + kq1 + kq2 + kq3 (exact fp32, fixed order); 4 outputs/thread
    {
        int r  = t >> 3;                  // 64 rows, 8 threads/row
        int c0 = (t & 7) * 4;             // 4 cols each
        int rtile = r >> 5, rr = r & 31;
        float4 b = *(const float4*)&bias[ct * 32 + c0];
        float s[4] = {b.x, b.y, b.z, b.w};
        #pragma unroll
        for (int q = 0; q < 4; ++q)
            #pragma unroll
            for (int j = 0; j < 4; ++j)
                s[j] += red[rtile * 4 + q][rr * 33 + c0 + j];
        float4 o = {s[0], s[1], s[2], s[3]};
        *(float4*)&out[(size_t)(row0 + r) * C_ + ct * 32 + c0] = o;
    }
}

extern "C" void kernel_launch(void* const* d_in, const int* in_sizes, int n_in,
                              void* d_out, int out_size, void* d_ws, size_t ws_size,
                              hipStream_t stream)
{
    const float* x    = (const float*)d_in[0];
    const float* bias = (const float*)d_in[1];
    const float* W1   = (const float*)d_in[2];
    const float* W2   = (const float*)d_in[3];
    const float* W3   = (const float*)d_in[4];
    // idx1/idx2/idx3 (d_in[5..7]) are deterministic lexicographic combinations -> baked at compile time
    float* out = (float*)d_out;
    (void)d_ws; (void)ws_size;            // no workspace needed anymore

    dim3 grid(B_ / 64, C_ / 32);          // 64 x 4 = 256 blocks, 512 thr = 8 waves/CU
    poly_mfma<<<grid, 512, 0, stream>>>(x, W1, W2, W3, bias, out);
}

// Round 12
// 86.698 us; speedup vs baseline: 1.0141x; 1.0141x over previous
//
#include <hip/hip_runtime.h>
#include <hip/hip_bf16.h>

// out[4096,128] = bias + P @ W; P[r][k] = prod of x[r, subset_k], subsets are
// ALL k-combinations of range(32) in lexicographic order -> compile-time schedule.
// Block = 32 rows x 64 cols, 512 threads = 8 waves = 8 K-eighths; each chunk's
// product set feeds TWO MFMAs (2 col-tiles) -> halves product-VALU duplication
// vs 32x32 blocks, at the same 2 waves/SIMD occupancy (R9 showed 1 wave/SIMD
// is a trap; R8 proved 2 is enough). LDS fp32 reduce of 8 K-partials -> out.
constexpr int B_   = 4096;
constexpr int C_   = 128;
constexpr int K1   = 32;
constexpr int K2   = 496;
constexpr int K3   = 4960;
constexpr int KTOT = K1 + K2 + K3;    // 5488 = 343 * 16 exactly -> no pad chunks
constexpr int NCH  = KTOT / 16;       // 343 chunks of K=16
// K-eighth boundaries (chunks): 43*7 + 42
constexpr int E0=0, E1=43, E2=86, E3=129, E4=172, E5=215, E6=258, E7=301, E8=NCH;

typedef __attribute__((ext_vector_type(8)))  short bf16x8;
typedef __attribute__((ext_vector_type(16))) float f32x16;

// ws layout
constexpr size_t WS_WT = 0;   // swizzled bf16 W: 343 chunks * 4 ct * 64 lanes * 16B = 1404928 B

// ---- compile-time subset schedule (lexicographic combinations; idx 32 -> xv[32]=1.0) ----
struct Sched { short a[KTOT]; short b[KTOT]; short c[KTOT]; };
constexpr Sched make_sched() {
    Sched s{}; int k = 0;
    for (int i = 0; i < 32; ++i) { s.a[k] = i; s.b[k] = 32; s.c[k] = 32; ++k; }
    for (int i = 0; i < 32; ++i)
        for (int j = i + 1; j < 32; ++j) { s.a[k] = i; s.b[k] = j; s.c[k] = 32; ++k; }
    for (int i = 0; i < 32; ++i)
        for (int j = i + 1; j < 32; ++j)
            for (int l = j + 1; l < 32; ++l) { s.a[k] = i; s.b[k] = j; s.c[k] = l; ++k; }
    return s;
}
constexpr Sched SCH = make_sched();

template<int K>
__device__ __forceinline__ float prodK(const float (&xv)[33]) {
    return xv[SCH.a[K]] * xv[SCH.b[K]] * xv[SCH.c[K]];   // static reg indices; pab CSE'd
}

template<int K0, int J>
__device__ __forceinline__ void prods8(const float (&xv)[33], bool hi, float (&q)[8]) {
    if constexpr (J < 8) {
        q[J] = hi ? prodK<K0 + 8 + J>(xv) : prodK<K0 + J>(xv);   // kg select
        prods8<K0, J + 1>(xv, hi, q);
    }
}

// chunks [CH, CHEND): one product set -> two B-frags / two MFMAs (col-tiles ct0, ct0+1)
template<int CH, int CHEND>
__device__ __forceinline__ void run_chunks(const float (&xv)[33], bool hi, int lane, int ct0,
                                           const ushort* __restrict__ Wb,
                                           f32x16& acc0, f32x16& acc1) {
    if constexpr (CH < CHEND) {
        constexpr int K0 = CH * 16;
        const ushort* wp = Wb + ((size_t)(CH * 4 + ct0) * 64 + lane) * 8;
        bf16x8 b0 = *(const bf16x8*)wp;               // 1KB coalesced per wave-load
        bf16x8 b1 = *(const bf16x8*)(wp + 64 * 8);    // next col-tile frag-block
        float q[8];
        prods8<K0, 0>(xv, hi, q);
        union { ushort us[8]; bf16x8 v; } af;
        #pragma unroll
        for (int j = 0; j < 8; ++j) {
            __hip_bfloat16 h = __float2bfloat16(q[j]);
            af.us[j] = *reinterpret_cast<ushort*>(&h);
        }
        acc0 = __builtin_amdgcn_mfma_f32_32x32x16_bf16(af.v, b0, acc0, 0, 0, 0);
        acc1 = __builtin_amdgcn_mfma_f32_32x32x16_bf16(af.v, b1, acc1, 0, 0, 0);
        run_chunks<CH + 1, CHEND>(xv, hi, lane, ct0, Wb, acc0, acc1);
    }
}

// prep: W (fp32 [k][c]) -> swizzled bf16 B-frag table matching the wave load pattern
__global__ __launch_bounds__(256)
void prep_wt(const float* __restrict__ W1,
             const float* __restrict__ W2,
             const float* __restrict__ W3,
             ushort* __restrict__ Wb)
{
    __shared__ ushort tile[16 * 130];
    const int gc = blockIdx.x, t = threadIdx.x;
    const int k0 = gc * 16;
    #pragma unroll
    for (int p = 0; p < 2; ++p) {
        int e  = p * 256 + t;                 // 512 float4 groups = 16k x 32cq
        int kk = e >> 5, cq = e & 31;
        int k  = k0 + kk;
        float4 v = {0.f, 0.f, 0.f, 0.f};
        if (k < K1)           v = ((const float4*)W1)[k * 32 + cq];
        else if (k < K1 + K2) v = ((const float4*)W2)[(k - K1) * 32 + cq];
        else if (k < KTOT)    v = ((const float4*)W3)[(k - K1 - K2) * 32 + cq];
        union { ushort u[4]; uint2 d; } o;
        __hip_bfloat16 h0 = __float2bfloat16(v.x); o.u[0] = *(ushort*)&h0;
        __hip_bfloat16 h1 = __float2bfloat16(v.y); o.u[1] = *(ushort*)&h1;
        __hip_bfloat16 h2 = __float2bfloat16(v.z); o.u[2] = *(ushort*)&h2;
        __hip_bfloat16 h3 = __float2bfloat16(v.w); o.u[3] = *(ushort*)&h3;
        *(uint2*)&tile[kk * 130 + cq * 4] = o.d;
    }
    __syncthreads();
    {
        int ct = t >> 6, lane = t & 63, n = lane & 31, kg = lane >> 5;
        union { ushort us[8]; uint4 d; } o;
        #pragma unroll
        for (int j = 0; j < 8; ++j) o.us[j] = tile[(kg * 8 + j) * 130 + ct * 32 + n];
        *(uint4*)&Wb[((size_t)(gc * 4 + ct) * 64 + lane) * 8] = o.d;
    }
}

// main: 32 rows x 64 cols, 8 waves = 8 K-eighths; LDS fp32 reduce of 8 partials
__global__ __launch_bounds__(512, 2)
void poly_mfma(const float* __restrict__ x,
               const ushort* __restrict__ Wb,
               const float* __restrict__ bias,
               float* __restrict__ out)
{
    __shared__ float red[8][32 * 66];     // 8 wave-partials of 32x64; stride 66 -> 2-way max

    const int t    = threadIdx.x;
    const int lane = t & 63;
    const int w    = t >> 6;              // wave id = K-eighth
    const int m    = lane & 31;           // A row lane index / C col index
    const bool hi  = lane >= 32;          // kg
    const int row0 = blockIdx.x * 32;
    const int ct0  = blockIdx.y * 2;      // col tiles ct0, ct0+1 -> cols [ct0*32, ct0*32+64)

    // lane's row -> 33 statically-indexed VGPRs (xv[32]=1.0 handles order<3)
    float xv[33];
    {
        const float4* xrow = (const float4*)(x + (size_t)(row0 + m) * 32);
        #pragma unroll
        for (int qv = 0; qv < 8; ++qv) {
            float4 v = xrow[qv];
            xv[qv * 4 + 0] = v.x; xv[qv * 4 + 1] = v.y;
            xv[qv * 4 + 2] = v.z; xv[qv * 4 + 3] = v.w;
        }
        xv[32] = 1.0f;
    }

    f32x16 acc0, acc1;
    #pragma unroll
    for (int i = 0; i < 16; ++i) { acc0[i] = 0.f; acc1[i] = 0.f; }

    switch (w) {
        case 0:  run_chunks<E0, E1>(xv, hi, lane, ct0, Wb, acc0, acc1); break;
        case 1:  run_chunks<E1, E2>(xv, hi, lane, ct0, Wb, acc0, acc1); break;
        case 2:  run_chunks<E2, E3>(xv, hi, lane, ct0, Wb, acc0, acc1); break;
        case 3:  run_chunks<E3, E4>(xv, hi, lane, ct0, Wb, acc0, acc1); break;
        case 4:  run_chunks<E4, E5>(xv, hi, lane, ct0, Wb, acc0, acc1); break;
        case 5:  run_chunks<E5, E6>(xv, hi, lane, ct0, Wb, acc0, acc1); break;
        case 6:  run_chunks<E6, E7>(xv, hi, lane, ct0, Wb, acc0, acc1); break;
        default: run_chunks<E7, E8>(xv, hi, lane, ct0, Wb, acc0, acc1); break;
    }

    // C/D layout (verified): col = lane&31, row = (e&3) + 8*(e>>2) + 4*kg
    const int kg = hi ? 1 : 0;
    #pragma unroll
    for (int e = 0; e < 16; ++e) {
        int r = (e & 3) + 8 * (e >> 2) + 4 * kg;
        red[w][r * 66 + m]      = acc0[e];
        red[w][r * 66 + 32 + m] = acc1[e];
    }
    __syncthreads();

    // out = bias + sum of 8 K-partials (exact fp32, fixed order); 4 outputs/thread
    {
        int r  = t >> 4;                  // 32 rows, 16 threads/row
        int c0 = (t & 15) * 4;            // 4 cols each (of 64)
        float4 b = *(const float4*)&bias[ct0 * 32 + c0];
        float s[4] = {b.x, b.y, b.z, b.w};
        #pragma unroll
        for (int q = 0; q < 8; ++q)
            #pragma unroll
            for (int j = 0; j < 4; ++j)
                s[j] += red[q][r * 66 + c0 + j];
        float4 o = {s[0], s[1], s[2], s[3]};
        *(float4*)&out[(size_t)(row0 + r) * C_ + ct0 * 32 + c0] = o;
    }
}

extern "C" void kernel_launch(void* const* d_in, const int* in_sizes, int n_in,
                              void* d_out, int out_size, void* d_ws, size_t ws_size,
                              hipStream_t stream)
{
    const float* x    = (const float*)d_in[0];
    const float* bias = (const float*)d_in[1];
    const float* W1   = (const float*)d_in[2];
    const float* W2   = (const float*)d_in[3];
    const float* W3   = (const float*)d_in[4];
    // idx1/idx2/idx3 (d_in[5..7]) are deterministic lexicographic combinations -> baked at compile time
    float* out = (float*)d_out;

    ushort* Wb = (ushort*)((char*)d_ws + WS_WT);

    prep_wt<<<NCH, 256, 0, stream>>>(W1, W2, W3, Wb);   // 343 blocks

    dim3 grid(B_ / 32, C_ / 64);          // 128 x 2 = 256 blocks, 512 thr = 2 waves/SIMD
    poly_mfma<<<grid, 512, 0, stream>>>(x, Wb, bias, out);
}

// Round 13
// 82.173 us; speedup vs baseline: 1.0700x; 1.0551x over previous
//
#include <hip/hip_runtime.h>
#include <hip/hip_bf16.h>

// out[4096,128] = bias + P @ W; P[r][k] = prod of x[r, subset_k], subsets are
// ALL k-combinations of range(32) in lexicographic order -> compile-time schedule.
// Structure (best measured: R8, 82.45 us): block = 32 rows x 32 cols; K split
// 4-way ACROSS WAVES of the block; LDS fp32 reduction -> direct out write.
// No cross-block coupling, no fences, no atomics. 512 blocks = 2/CU.
constexpr int B_   = 4096;
constexpr int C_   = 128;
constexpr int K1   = 32;
constexpr int K2   = 496;
constexpr int K3   = 4960;
constexpr int KTOT = K1 + K2 + K3;   // 5488
constexpr int KPAD = 5632;           // pads: product=1.0 * W-row=0 -> contributes 0

constexpr int NCHUNK = KPAD / 16;    // 352 chunks of K=16 (one 32x32x16 MFMA each)
constexpr int WCH    = NCHUNK / 4;   // 88 chunks per wave (K-quarter)

typedef __attribute__((ext_vector_type(8)))  short bf16x8;
typedef __attribute__((ext_vector_type(16))) float f32x16;

// ws layout
constexpr size_t WS_WT = 0;          // swizzled bf16 W: 352 chunks * 4 ct * 64 lanes * 16B = 1441792

// ---- compile-time subset schedule (lexicographic combinations, pads -> idx 32 = 1.0) ----
struct Sched { short a[KPAD]; short b[KPAD]; short c[KPAD]; };
constexpr Sched make_sched() {
    Sched s{}; int k = 0;
    for (int i = 0; i < 32; ++i) { s.a[k] = i; s.b[k] = 32; s.c[k] = 32; ++k; }
    for (int i = 0; i < 32; ++i)
        for (int j = i + 1; j < 32; ++j) { s.a[k] = i; s.b[k] = j; s.c[k] = 32; ++k; }
    for (int i = 0; i < 32; ++i)
        for (int j = i + 1; j < 32; ++j)
            for (int l = j + 1; l < 32; ++l) { s.a[k] = i; s.b[k] = j; s.c[k] = l; ++k; }
    for (; k < KPAD; ++k) { s.a[k] = 32; s.b[k] = 32; s.c[k] = 32; }  // W rows zeroed
    return s;
}
constexpr Sched SCH = make_sched();

template<int K>
__device__ __forceinline__ float prodK(const float (&xv)[33]) {
    return xv[SCH.a[K]] * xv[SCH.b[K]] * xv[SCH.c[K]];   // static reg indices; pab CSE'd
}

template<int K0, int J>
__device__ __forceinline__ void prods8(const float (&xv)[33], bool hi, float (&q)[8]) {
    if constexpr (J < 8) {
        q[J] = hi ? prodK<K0 + 8 + J>(xv) : prodK<K0 + J>(xv);   // kg select
        prods8<K0, J + 1>(xv, hi, q);
    }
}

// wave WV processes chunks [WV*WCH, (WV+1)*WCH) of the global chunk list
template<int WV, int CH>
__device__ __forceinline__ void run_chunks(const float (&xv)[33], bool hi, int lane, int ct,
                                           const ushort* __restrict__ Wb, f32x16& acc) {
    if constexpr (CH < WCH) {
        constexpr int G  = WV * WCH + CH;        // global chunk id, K0 = G*16
        constexpr int K0 = G * 16;
        // B-frag from L2-resident swizzled table: 1KB coalesced per wave-load
        bf16x8 b0 = *(const bf16x8*)(Wb + ((size_t)(G * 4 + ct) * 64 + lane) * 8);
        // A-frag: lane's own 8 products, pure register VALU
        float q[8];
        prods8<K0, 0>(xv, hi, q);
        union { ushort us[8]; bf16x8 v; } af;
        #pragma unroll
        for (int j = 0; j < 8; ++j) {
            __hip_bfloat16 h = __float2bfloat16(q[j]);
            af.us[j] = *reinterpret_cast<ushort*>(&h);
        }
        acc = __builtin_amdgcn_mfma_f32_32x32x16_bf16(af.v, b0, acc, 0, 0, 0);
        run_chunks<WV, CH + 1>(xv, hi, lane, ct, Wb, acc);
    }
}

// prep: W (fp32 [k][c]) -> swizzled bf16 B-frag table matching the wave load pattern
__global__ __launch_bounds__(256)
void prep_wt(const float* __restrict__ W1,
             const float* __restrict__ W2,
             const float* __restrict__ W3,
             ushort* __restrict__ Wb)
{
    __shared__ ushort tile[16 * 130];
    const int gc = blockIdx.x, t = threadIdx.x;
    const int k0 = gc * 16;
    #pragma unroll
    for (int p = 0; p < 2; ++p) {
        int e  = p * 256 + t;                 // 512 float4 groups = 16k x 32cq
        int kk = e >> 5, cq = e & 31;
        int k  = k0 + kk;
        float4 v = {0.f, 0.f, 0.f, 0.f};
        if (k < K1)           v = ((const float4*)W1)[k * 32 + cq];
        else if (k < K1 + K2) v = ((const float4*)W2)[(k - K1) * 32 + cq];
        else if (k < KTOT)    v = ((const float4*)W3)[(k - K1 - K2) * 32 + cq];
        union { ushort u[4]; uint2 d; } o;
        __hip_bfloat16 h0 = __float2bfloat16(v.x); o.u[0] = *(ushort*)&h0;
        __hip_bfloat16 h1 = __float2bfloat16(v.y); o.u[1] = *(ushort*)&h1;
        __hip_bfloat16 h2 = __float2bfloat16(v.z); o.u[2] = *(ushort*)&h2;
        __hip_bfloat16 h3 = __float2bfloat16(v.w); o.u[3] = *(ushort*)&h3;
        *(uint2*)&tile[kk * 130 + cq * 4] = o.d;
    }
    __syncthreads();
    {
        int ct = t >> 6, lane = t & 63, n = lane & 31, kg = lane >> 5;
        union { ushort us[8]; uint4 d; } o;
        #pragma unroll
        for (int j = 0; j < 8; ++j) o.us[j] = tile[(kg * 8 + j) * 130 + ct * 32 + n];
        *(uint4*)&Wb[((size_t)(gc * 4 + ct) * 64 + lane) * 8] = o.d;
    }
}

// main: 4 waves = 4 K-quarters of one 32x32 tile; LDS fp32 reduce; direct out write
__global__ __launch_bounds__(256, 2)
void poly_mfma(const float* __restrict__ x,
               const ushort* __restrict__ Wb,
               const float* __restrict__ bias,
               float* __restrict__ out)
{
    __shared__ float red[4][32 * 33];     // 4 wave-accs, stride 33 -> 2-way max (free)

    const int t    = threadIdx.x;
    const int lane = t & 63;
    const int w    = t >> 6;              // wave id = K-quarter
    const int m    = lane & 31;           // A row / C col lane index
    const bool hi  = lane >= 32;          // kg
    const int row0 = blockIdx.x * 32;
    const int ct   = blockIdx.y;          // col tile: cols [ct*32, ct*32+32)

    // lane's row -> 33 statically-indexed VGPRs (xv[32]=1.0 handles order<3 + pads)
    float xv[33];
    {
        const float4* xrow = (const float4*)(x + (size_t)(row0 + m) * 32);
        #pragma unroll
        for (int qv = 0; qv < 8; ++qv) {
            float4 v = xrow[qv];
            xv[qv * 4 + 0] = v.x; xv[qv * 4 + 1] = v.y;
            xv[qv * 4 + 2] = v.z; xv[qv * 4 + 3] = v.w;
        }
        xv[32] = 1.0f;
    }

    f32x16 acc;
    #pragma unroll
    for (int i = 0; i < 16; ++i) acc[i] = 0.f;

    switch (w) {
        case 0:  run_chunks<0, 0>(xv, hi, lane, ct, Wb, acc); break;
        case 1:  run_chunks<1, 0>(xv, hi, lane, ct, Wb, acc); break;
        case 2:  run_chunks<2, 0>(xv, hi, lane, ct, Wb, acc); break;
        default: run_chunks<3, 0>(xv, hi, lane, ct, Wb, acc); break;
    }

    // C/D layout (verified): col = lane&31, row = (e&3) + 8*(e>>2) + 4*kg
    const int kg = hi ? 1 : 0;
    #pragma unroll
    for (int e = 0; e < 16; ++e) {
        int r = (e & 3) + 8 * (e >> 2) + 4 * kg;
        red[w][r * 33 + m] = acc[e];
    }
    __syncthreads();

    // reduce: out = bias + w0 + w1 + w2 + w3 (exact fp32, fixed order)
    {
        int r  = t >> 3;                  // 32 rows, 8 threads/row
        int c0 = (t & 7) * 4;             // 4 cols each
        float4 b = *(const float4*)&bias[ct * 32 + c0];
        float s[4] = {b.x, b.y, b.z, b.w};
        #pragma unroll
        for (int wv = 0; wv < 4; ++wv)
            #pragma unroll
            for (int j = 0; j < 4; ++j)
                s[j] += red[wv][r * 33 + c0 + j];
        float4 o = {s[0], s[1], s[2], s[3]};
        *(float4*)&out[(size_t)(row0 + r) * C_ + ct * 32 + c0] = o;
    }
}

extern "C" void kernel_launch(void* const* d_in, const int* in_sizes, int n_in,
                              void* d_out, int out_size, void* d_ws, size_t ws_size,
                              hipStream_t stream)
{
    const float* x    = (const float*)d_in[0];
    const float* bias = (const float*)d_in[1];
    const float* W1   = (const float*)d_in[2];
    const float* W2   = (const float*)d_in[3];
    const float* W3   = (const float*)d_in[4];
    // idx1/idx2/idx3 (d_in[5..7]) are deterministic lexicographic combinations -> baked at compile time
    float* out = (float*)d_out;

    ushort* Wb = (ushort*)((char*)d_ws + WS_WT);

    prep_wt<<<KPAD / 16, 256, 0, stream>>>(W1, W2, W3, Wb);

    dim3 grid(B_ / 32, C_ / 32);          // 128 x 4 = 512 blocks = 2/CU
    poly_mfma<<<grid, 256, 0, stream>>>(x, Wb, bias, out);
}